// Round 11
// baseline (358.788 us; speedup 1.0000x reference)
//
#include <hip/hip_runtime.h>
#include <hip/hip_bf16.h>

#define S_LEN 2048
#define HID_D 2048
#define NHEAD 16
#define QLORA 1536
#define KVLORA 512
#define DNOPE 128
#define DROPE 64
#define DV 128
#define DQK 192
#define NCAT 2176           // QLORA + 640 (ckv padded): fused stage-1 N

#define KS_SH (64 * 192)    // 12288 shorts (24576 B) K buffer
#define VS_SH (128 * 64)    // 8192 shorts (16384 B) V buffer
#define BUF_SH (KS_SH + VS_SH)  // 40960 B per buffer; x2 = 81920 B -> 2 blocks/CU

typedef __hip_bfloat16 bf16;
typedef __attribute__((ext_vector_type(8))) short short8;
typedef __attribute__((ext_vector_type(4))) short s16x4;
typedef __attribute__((ext_vector_type(4))) float f32x4;

__device__ __forceinline__ float ldE(const float* p) { return *p; }
__device__ __forceinline__ float ldE(const bf16* p) { return __bfloat162float(*p); }
__device__ __forceinline__ void stE(float* p, float v) { *p = v; }
__device__ __forceinline__ void stE(bf16* p, float v) { *p = __float2bfloat16(v); }

__device__ __forceinline__ short bf16bits(float v) {
    __hip_bfloat16 h = __float2bfloat16(v);
    return *reinterpret_cast<short*>(&h);
}

// bf16 bit-pattern (as short, BY VALUE) -> float
__device__ __forceinline__ float b2f(short s) {
    union { short s; bf16 h; } u;
    u.s = s;
    return __bfloat162float(u.h);
}

__device__ __forceinline__ f32x4 mfma16(short8 a, short8 b, f32x4 c) {
    return __builtin_amdgcn_mfma_f32_16x16x32_bf16(a, b, c, 0, 0, 0);
}

// async global->LDS, 16B/lane. LDS dest = wave-uniform base + lane*16 (HW adds it).
__device__ __forceinline__ void gload16(const void* g, void* l) {
    __builtin_amdgcn_global_load_lds(
        (const __attribute__((address_space(1))) unsigned int*)g,
        (__attribute__((address_space(3))) unsigned int*)l, 16, 0, 0);
}

// Detect fp32 vs bf16 inputs by sniffing `hidden` as bf16 (parallel, 256 thr).
__global__ void detect_kernel(const void* hidden, int* flag) {
    __shared__ int red[256];
    const int tid = threadIdx.x;
    const bf16* hb = (const bf16*)hidden;
    float a = fabsf(__bfloat162float(hb[tid]));
    red[tid] = (!(a < 64.f) || (a != 0.f && a < 1e-30f)) ? 1 : 0;
    __syncthreads();
    for (int o = 128; o > 0; o >>= 1) {
        if (tid < o) red[tid] += red[tid + o];
        __syncthreads();
    }
    if (tid == 0) *flag = (red[0] > 16) ? 1 : 0;  // 1 => fp32
}

// Generic 64x64-tile transpose body: out[roff + n][KDIM] = in[k][n], zero n>=N.
template <int KDIM>
__device__ void transpose_tile(const void* in, bf16* out, int N, int n0, int k0,
                               int roff, int fp32) {
    __shared__ __align__(16) short Ts[64][80];
    const int tid = threadIdx.x;
    const bool inb = n0 < N;
    const int kl = tid >> 4;
    const int nl = (tid & 15) * 4;
#pragma unroll
    for (int p = 0; p < 4; ++p) {
        int k = kl + p * 16;
        float v[4] = {0.f, 0.f, 0.f, 0.f};
        if (inb) {
            if (fp32) {
                const float4 f = *(const float4*)((const float*)in + (size_t)(k0 + k) * N + n0 + nl);
                v[0] = f.x; v[1] = f.y; v[2] = f.z; v[3] = f.w;
            } else {
                const bf16* bp = (const bf16*)in + (size_t)(k0 + k) * N + n0 + nl;
#pragma unroll
                for (int i = 0; i < 4; ++i) v[i] = __bfloat162float(bp[i]);
            }
        }
#pragma unroll
        for (int i = 0; i < 4; ++i) Ts[nl + i][k] = bf16bits(v[i]);
    }
    __syncthreads();
    const int nr = tid >> 2;
    const int kq = (tid & 3) * 16;
    short* op = (short*)out + (size_t)(roff + n0 + nr) * KDIM + k0 + kq;
    *(short8*)op = *(short8*)&Ts[nr][kq];
    *(short8*)(op + 8) = *(short8*)&Ts[nr][kq + 8];
}

// Fused: blocks 0..2047 convert hidden -> hbf (bf16, 8 el/thread);
// blocks 2048..3135 transpose w_qa||w_kva -> BtCat (stage-1 weights).
__global__ void prep1_kernel(const void* hidden, bf16* hbf,
                             const void* w_qa, const void* w_kva, bf16* BtCat,
                             const int* flag) {
    const int bid = blockIdx.x;
    if (bid < 2048) {
        const int i = bid * 256 + threadIdx.x;  // < 524288 always
        size_t off = (size_t)i * 8;
        short8 o;
        if (*flag) {
            const float* f = (const float*)hidden + off;
#pragma unroll
            for (int j = 0; j < 8; ++j) o[j] = bf16bits(f[j]);
        } else {
            o = *(const short8*)((const short*)hidden + off);
        }
        *(short8*)((short*)hbf + off) = o;
    } else {
        const int b = bid - 2048;       // 0..1087
        const int bx = b % 34;
        const int k0 = (b / 34) * 64;
        const int fp32 = *flag;
        if (bx < 24) transpose_tile<HID_D>(w_qa, BtCat, QLORA, bx * 64, k0, 0, fp32);
        else transpose_tile<HID_D>(w_kva, BtCat, KVLORA + DROPE, (bx - 24) * 64, k0, QLORA, fp32);
    }
}

template <typename TG>
__device__ void rmsnorm_row(const bf16* __restrict__ xr, const TG* __restrict__ g,
                            bf16* __restrict__ yr, int len) {
    const int tid = threadIdx.x;
    float ss = 0.f;
    for (int i = tid; i < len; i += 256) {
        float v = __bfloat162float(xr[i]);
        ss += v * v;
    }
    __shared__ float red[256];
    red[tid] = ss;
    __syncthreads();
    for (int o = 128; o > 0; o >>= 1) {
        if (tid < o) red[tid] += red[tid + o];
        __syncthreads();
    }
    const float scale = rsqrtf(red[0] / (float)len + 1e-6f);
    for (int i = tid; i < len; i += 256)
        yr[i] = __float2bfloat16(__bfloat162float(xr[i]) * scale * ldE(&g[i]));
}

// Fused: blocks 0..4095 rmsnorm (q_a in place stride NCAT; ckv -> ckvn);
// blocks 4096..5759 transpose w_qb -> wqbT and w_kvb -> wkvbT.
__global__ void prep2_kernel(bf16* qk, const void* g_qa, const void* g_kva, bf16* ckvn,
                             const void* w_qb, bf16* wqbT,
                             const void* w_kvb, bf16* wkvbT, const int* flag) {
    const int bid = blockIdx.x;
    if (bid < 2 * S_LEN) {
        if (*flag) {
            if (bid < S_LEN)
                rmsnorm_row<float>(qk + (size_t)bid * NCAT, (const float*)g_qa,
                                   qk + (size_t)bid * NCAT, QLORA);
            else {
                const int s = bid - S_LEN;
                rmsnorm_row<float>(qk + (size_t)s * NCAT + QLORA, (const float*)g_kva,
                                   ckvn + (size_t)s * KVLORA, KVLORA);
            }
        } else {
            if (bid < S_LEN)
                rmsnorm_row<bf16>(qk + (size_t)bid * NCAT, (const bf16*)g_qa,
                                  qk + (size_t)bid * NCAT, QLORA);
            else {
                const int s = bid - S_LEN;
                rmsnorm_row<bf16>(qk + (size_t)s * NCAT + QLORA, (const bf16*)g_kva,
                                  ckvn + (size_t)s * KVLORA, KVLORA);
            }
        }
    } else {
        const int b = bid - 2 * S_LEN;   // 0..1663
        const int fp32 = *flag;
        if (b < 1152) {
            const int n0 = (b % 48) * 64, k0 = (b / 48) * 64;
            transpose_tile<QLORA>(w_qb, wqbT, NHEAD * DQK, n0, k0, 0, fp32);
        } else {
            const int bb = b - 1152;
            const int n0 = (bb % 64) * 64, k0 = (bb / 64) * 64;
            transpose_tile<KVLORA>(w_kvb, wkvbT, NHEAD * (DNOPE + DV), n0, k0, 0, fp32);
        }
    }
}

// C[M][N] = A[M][K] @ Bt[N][K]^T, bf16 in, fp32 acc. 128x128 tile, BK=64,
// 4 waves 2x2, each 64x64 = 4x4 mfma_16x16x32. TRIPLE-BUFFERED LDS (3x32KB,
// allocated ONCE in the wrapper and passed in — two inlined bodies would
// otherwise double-allocate 96KB each and blow the 160KB limit) with 2-DEEP
// issue-ahead global_load_lds + counted s_waitcnt vmcnt(16): two K-steps'
// loads stay in flight so the full L2/L3 latency (~200-900cy) hides under
// compute (grids are ~1 block/CU -> no cross-block hiding).
// LDS [row][64], chunk c at pos c^(row&7): 0 conflicts. XCD-chunked swizzle.
// MODE 0: bf16 C. MODE 1: dtype by flag. MODE 2: KV split epilogue.
template <int MODE, typename TC>
__device__ void mgemm_body(short* __restrict__ AB,  // shared, 3*16384 shorts
                           const bf16* __restrict__ A, int lda,
                           const bf16* __restrict__ Bt, int ldb,
                           TC* __restrict__ C, int ldc, int K,
                           bf16* __restrict__ Kn, bf16* __restrict__ Vt) {
    const int tid = threadIdx.x;
    const int w = tid >> 6, lane = tid & 63;
    const int lg = lane >> 4, ln = lane & 15;
    const int wm = w >> 1, wn = w & 1;

    // XCD-chunked swizzle: blocks with flat%8==x run on XCD x (round-robin
    // dispatch) and receive the contiguous work chunk [x*cpx, (x+1)*cpx).
    const int nbx = gridDim.x;
    const int flat = blockIdx.y * nbx + blockIdx.x;
    const int cpx = (nbx * gridDim.y) >> 3;
    const int swz = (flat & 7) * cpx + (flat >> 3);
    const int m0 = (swz / nbx) * 128, n0 = (swz % nbx) * 128;

    int aO[4], bO[4];
#pragma unroll
    for (int p = 0; p < 4; ++p) {
        const int cid = tid + p * 256;
        const int row = cid >> 3, cpos = cid & 7;
        const int c = cpos ^ (row & 7);
        aO[p] = (m0 + row) * lda + c * 8;
        bO[p] = (n0 + row) * ldb + c * 8;
    }
    int aoff[2][4], boff[2][4];
#pragma unroll
    for (int hk = 0; hk < 2; ++hk)
#pragma unroll
        for (int i = 0; i < 4; ++i) {
            const int ra = wm * 64 + i * 16 + ln;
            const int rb = wn * 64 + i * 16 + ln;
            aoff[hk][i] = ra * 64 + ((hk * 4 + lg) ^ (ra & 7)) * 8;
            boff[hk][i] = rb * 64 + ((hk * 4 + lg) ^ (rb & 7)) * 8;
        }

    f32x4 acc[4][4];
#pragma unroll
    for (int i = 0; i < 4; ++i)
#pragma unroll
        for (int j = 0; j < 4; ++j) acc[i][j] = (f32x4){0.f, 0.f, 0.f, 0.f};

    const int nsteps = K >> 6;
    // Prologue: stage steps 0 and 1 into buffers 0 and 1.
#pragma unroll
    for (int p = 0; p < 4; ++p) {
        gload16(A + (size_t)aO[p], AB + (w + 4 * p) * 512);
        gload16(Bt + (size_t)bO[p], AB + 8192 + (w + 4 * p) * 512);
    }
    if (nsteps > 1) {
#pragma unroll
        for (int p = 0; p < 4; ++p) {
            gload16(A + (size_t)aO[p] + 64, AB + 16384 + (w + 4 * p) * 512);
            gload16(Bt + (size_t)bO[p] + 64, AB + 16384 + 8192 + (w + 4 * p) * 512);
        }
    }

    int cur = 0;
    for (int s = 0; s < nsteps; ++s) {
        // Issue step s+2 into buf[(cur+2)%3] (its last reader was step s-1,
        // whose end barrier precedes this point), then counted-wait for step s.
        if (s + 2 < nsteps) {
            int pre = cur + 2; if (pre >= 3) pre -= 3;
            const int k0n = (s + 2) * 64;
            short* AsN = AB + pre * 16384;
            short* BsN = AsN + 8192;
#pragma unroll
            for (int p = 0; p < 4; ++p) {
                gload16(A + (size_t)aO[p] + k0n, AsN + (w + 4 * p) * 512);
                gload16(Bt + (size_t)bO[p] + k0n, BsN + (w + 4 * p) * 512);
            }
            asm volatile("s_waitcnt vmcnt(16)" ::: "memory");
        } else if (s + 1 < nsteps) {
            asm volatile("s_waitcnt vmcnt(8)" ::: "memory");
        } else {
            asm volatile("s_waitcnt vmcnt(0)" ::: "memory");
        }
        __builtin_amdgcn_s_barrier();  // step s's A/B visible to all waves
        const short* As = AB + cur * 16384;
        const short* Bs = As + 8192;
        __builtin_amdgcn_s_setprio(1);
#pragma unroll
        for (int hk = 0; hk < 2; ++hk) {
            short8 af[4], bfr[4];
#pragma unroll
            for (int i = 0; i < 4; ++i) af[i] = *(const short8*)&As[aoff[hk][i]];
#pragma unroll
            for (int j = 0; j < 4; ++j) bfr[j] = *(const short8*)&Bs[boff[hk][j]];
#pragma unroll
            for (int i = 0; i < 4; ++i)
#pragma unroll
                for (int j = 0; j < 4; ++j) acc[i][j] = mfma16(af[i], bfr[j], acc[i][j]);
        }
        __builtin_amdgcn_s_setprio(0);
        __builtin_amdgcn_s_barrier();  // buf[cur] consumed -> may be restaged
        cur = (cur + 1 == 3) ? 0 : cur + 1;
    }
    if constexpr (MODE == 2) {
#pragma unroll
        for (int i = 0; i < 4; ++i)
#pragma unroll
            for (int j = 0; j < 4; ++j) {
                const int col = n0 + wn * 64 + j * 16 + ln;
                const int row = m0 + wm * 64 + i * 16 + lg * 4;  // %4 == 0
                const int h = col >> 8, d = col & 255;
                if (d < DNOPE) {
                    bf16* cp = Kn + (size_t)row * (NHEAD * DNOPE) + h * DNOPE + d;
#pragma unroll
                    for (int r = 0; r < 4; ++r)
                        cp[(size_t)r * (NHEAD * DNOPE)] = __float2bfloat16(acc[i][j][r]);
                } else {
                    s16x4 pk;
#pragma unroll
                    for (int r = 0; r < 4; ++r) pk[r] = bf16bits(acc[i][j][r]);
                    *(s16x4*)(Vt + (size_t)(h * DV + (d - DNOPE)) * S_LEN + row) = pk;
                }
            }
    } else {
#pragma unroll
        for (int i = 0; i < 4; ++i)
#pragma unroll
            for (int j = 0; j < 4; ++j) {
                TC* cp = C + (size_t)(m0 + wm * 64 + i * 16 + lg * 4) * ldc + n0 + wn * 64 +
                         j * 16 + ln;
#pragma unroll
                for (int r = 0; r < 4; ++r)
                    stE(cp + (size_t)r * ldc, acc[i][j][r]);
            }
    }
}

template <int MODE>
__global__ __launch_bounds__(256, 1)
void mgemm_kernel(const bf16* A, int lda, const bf16* Bt, int ldb, void* C, int ldc,
                  int K, const int* flag, bf16* Kn, bf16* Vt) {
    __shared__ __align__(16) short AB[3][16384];  // single 96KB allocation
    if (MODE == 1 && *flag)
        mgemm_body<1, float>(&AB[0][0], A, lda, Bt, ldb, (float*)C, ldc, K, nullptr, nullptr);
    else if (MODE == 2)
        mgemm_body<2, bf16>(&AB[0][0], A, lda, Bt, ldb, (bf16*)C, ldc, K, Kn, Vt);
    else
        mgemm_body<0, bf16>(&AB[0][0], A, lda, Bt, ldb, (bf16*)C, ldc, K, nullptr, nullptr);
}

// RoPE (deinterleave form): out[p] = x[2p]*c - x[2p+1]*s; out[p+32] = x[2p+1]*c + x[2p]*s.
// ckv = qk_cat + QLORA (row stride NCAT); k_pe raw at ckv[s][KVLORA..].
template <typename TG>
__device__ void rope_body(bf16* __restrict__ q, const bf16* __restrict__ ckv,
                          bf16* __restrict__ kpe, const TG* __restrict__ cosb,
                          const TG* __restrict__ sinb) {
    const int s = blockIdx.x;
    const int tid = threadIdx.x;  // blockDim = 576
    float x0 = 0.f, x1 = 0.f, c = 0.f, sn = 0.f;
    bf16* qbase = nullptr;
    int p = 0;
    const bool isq = tid < 512;
    const bool active = tid < 544;
    if (active) {
        if (isq) {
            const int h = tid >> 5;
            p = tid & 31;
            qbase = q + (size_t)s * (NHEAD * DQK) + h * DQK + DNOPE;
            x0 = __bfloat162float(qbase[2 * p]);
            x1 = __bfloat162float(qbase[2 * p + 1]);
        } else {
            p = tid - 512;
            const bf16* kb = ckv + (size_t)s * NCAT + KVLORA;
            x0 = __bfloat162float(kb[2 * p]);
            x1 = __bfloat162float(kb[2 * p + 1]);
        }
        c = ldE(&cosb[s * 64 + p]);
        sn = ldE(&sinb[s * 64 + p]);
    }
    __syncthreads();
    if (active) {
        if (isq) {
            qbase[p] = __float2bfloat16(x0 * c - x1 * sn);
            qbase[p + 32] = __float2bfloat16(x1 * c + x0 * sn);
        } else {
            kpe[s * 64 + p] = __float2bfloat16(x0 * c - x1 * sn);
            kpe[s * 64 + p + 32] = __float2bfloat16(x1 * c + x0 * sn);
        }
    }
}

__global__ void rope_kernel(bf16* q, const bf16* ckv, bf16* kpe,
                            const void* cosb, const void* sinb, const int* flag) {
    if (*flag) rope_body<float>(q, ckv, kpe, (const float*)cosb, (const float*)sinb);
    else       rope_body<bf16>(q, ckv, kpe, (const bf16*)cosb, (const bf16*)sinb);
}

// Flash-style MFMA attention (unchanged: 128-row q-tiles, split-K <=11,
// XCD-swizzled grid 512, double-buffered staging w/ counted vmcnt).
__global__ __launch_bounds__(256, 2)
void fattn_kernel(const bf16* __restrict__ q, const bf16* __restrict__ kn,
                  const bf16* __restrict__ vt, const bf16* __restrict__ kpe,
                  bf16* __restrict__ attn, bf16* __restrict__ Opart, float* __restrict__ ml) {
    const int nf = blockIdx.x;       // 0..511
    const int xcd = nf & 7;
    const int j = nf >> 3;           // 0..63
    const int bx = j & 31;
    const int h = (j >> 5) * 8 + xcd;
    int qt, part, nparts;
    if (bx < 15)      { qt = 15 - bx / 3;        part = bx % 3;        nparts = 3; }
    else if (bx < 27) { qt = 10 - (bx - 15) / 2; part = (bx - 15) & 1; nparts = 2; }
    else              { qt = 31 - bx;            part = 0;             nparts = 1; }
    const int nt = 2 * qt + 2;
    const int bsz = nt / nparts, rr = nt % nparts;
    const int t0 = part * bsz + (part < rr ? part : rr);
    const int t1 = t0 + bsz + (part < rr ? 1 : 0);
    const int q0 = qt * 128;

    const int tid = threadIdx.x;
    const int w = tid >> 6;
    const int l = tid & 63;
    const int lg = l >> 4;
    const int ln = l & 15;

    __shared__ __align__(16) short KV[2][BUF_SH];

    int offK[6], sK[6];
    bool isn[6];
#pragma unroll
    for (int p = 0; p < 6; ++p) {
        const int cid = tid + p * 256;
        const int row = cid / 24;
        const int cpos = cid % 24;
        const int c = (cpos & 24) | ((cpos & 7) ^ (row & 7));
        if (c < 16) {
            offK[p] = row * (NHEAD * DNOPE) + h * DNOPE + c * 8;
            sK[p] = NHEAD * DNOPE;
            isn[p] = true;
        } else {
            offK[p] = row * DROPE + (c - 16) * 8;
            sK[p] = DROPE;
            isn[p] = false;
        }
    }
    int offV[4];
#pragma unroll
    for (int p = 0; p < 4; ++p) {
        const int cid = tid + p * 256;
        const int row = cid >> 3;
        const int cc = (cid & 7) ^ (row & 7);
        offV[p] = (h * DV + row) * S_LEN + cc * 8;
    }

    short8 qf[2][6];
#pragma unroll
    for (int i = 0; i < 2; ++i) {
        const short* qrow =
            (const short*)(q + (size_t)(q0 + i * 64 + w * 16 + ln) * (NHEAD * DQK) + h * DQK);
#pragma unroll
        for (int ks = 0; ks < 6; ++ks)
            qf[i][ks] = *(const short8*)(qrow + ks * 32 + lg * 8);
    }

    f32x4 O[2][8];
#pragma unroll
    for (int i = 0; i < 2; ++i)
#pragma unroll
        for (int ct = 0; ct < 8; ++ct) O[i][ct] = (f32x4){0.f, 0.f, 0.f, 0.f};
    float m_[2][4], l_[2][4];
#pragma unroll
    for (int i = 0; i < 2; ++i)
#pragma unroll
        for (int r = 0; r < 4; ++r) { m_[i][r] = -1e30f; l_[i][r] = 0.f; }
    const float scale = 0.07216878364870322f;  // 192^-0.5

    {
        const int k0 = t0 * 64;
#pragma unroll
        for (int p = 0; p < 6; ++p) {
            const bf16* sp = (isn[p] ? kn : kpe) + (size_t)offK[p] + (size_t)k0 * sK[p];
            gload16(sp, &KV[0][0] + (w + 4 * p) * 512);
        }
#pragma unroll
        for (int p = 0; p < 4; ++p)
            gload16(vt + (size_t)offV[p] + k0, &KV[0][KS_SH] + (w + 4 * p) * 512);
    }

    for (int t = t0; t < t1; ++t) {
        const int cur = (t - t0) & 1;
        short* Ks = &KV[cur][0];
        short* Vs = &KV[cur][KS_SH];
        if (t + 1 < t1) {
            const int k0n = (t + 1) * 64;
            short* KsN = &KV[cur ^ 1][0];
            short* VsN = &KV[cur ^ 1][KS_SH];
#pragma unroll
            for (int p = 0; p < 6; ++p) {
                const bf16* sp = (isn[p] ? kn : kpe) + (size_t)offK[p] + (size_t)k0n * sK[p];
                gload16(sp, KsN + (w + 4 * p) * 512);
            }
#pragma unroll
            for (int p = 0; p < 4; ++p)
                gload16(vt + (size_t)offV[p] + k0n, VsN + (w + 4 * p) * 512);
            asm volatile("s_waitcnt vmcnt(10)" ::: "memory");
        } else {
            asm volatile("s_waitcnt vmcnt(0)" ::: "memory");
        }
        __builtin_amdgcn_s_barrier();

        const int k0 = t * 64;
        f32x4 S[2][4];
#pragma unroll
        for (int i = 0; i < 2; ++i)
#pragma unroll
            for (int c = 0; c < 4; ++c) S[i][c] = (f32x4){0.f, 0.f, 0.f, 0.f};
        __builtin_amdgcn_s_setprio(1);
#pragma unroll
        for (int ks = 0; ks < 6; ++ks) {
            const int kch = ks * 4 + lg;
#pragma unroll
            for (int c = 0; c < 4; ++c) {
                short8 kf = *(const short8*)&Ks[(size_t)(c * 16 + ln) * 192 +
                                               (size_t)(kch ^ (ln & 7)) * 8];
                S[0][c] = mfma16(qf[0][ks], kf, S[0][c]);
                S[1][c] = mfma16(qf[1][ks], kf, S[1][c]);
            }
        }
        __builtin_amdgcn_s_setprio(0);

        const int d0 = k0 - q0;
#pragma unroll
        for (int i = 0; i < 2; ++i)
#pragma unroll
            for (int c = 0; c < 4; ++c)
#pragma unroll
                for (int r = 0; r < 4; ++r) {
                    float v = S[i][c][r] * scale;
                    if (d0 > -64 &&
                        (d0 + c * 16 + ln) > (i * 64 + w * 16 + lg * 4 + r)) v = -1e30f;
                    S[i][c][r] = v;
                }

        float alpha[2][4];
#pragma unroll
        for (int i = 0; i < 2; ++i)
#pragma unroll
            for (int r = 0; r < 4; ++r) {
                float mx = fmaxf(fmaxf(S[i][0][r], S[i][1][r]), fmaxf(S[i][2][r], S[i][3][r]));
#pragma unroll
                for (int d = 1; d < 16; d <<= 1) mx = fmaxf(mx, __shfl_xor(mx, d));
                float mn = fmaxf(m_[i][r], mx);
                alpha[i][r] = __expf(m_[i][r] - mn);
                m_[i][r] = mn;
                float rs = 0.f;
#pragma unroll
                for (int c = 0; c < 4; ++c) {
                    float p = __expf(S[i][c][r] - mn);
                    S[i][c][r] = p;
                    rs += p;
                }
#pragma unroll
                for (int d = 1; d < 16; d <<= 1) rs += __shfl_xor(rs, d);
                l_[i][r] = l_[i][r] * alpha[i][r] + rs;
            }
#pragma unroll
        for (int i = 0; i < 2; ++i)
#pragma unroll
            for (int ct = 0; ct < 8; ++ct)
#pragma unroll
                for (int r = 0; r < 4; ++r) O[i][ct][r] *= alpha[i][r];

        __builtin_amdgcn_s_barrier();
        short* Pb = Ks;
#pragma unroll
        for (int i = 0; i < 2; ++i)
#pragma unroll
            for (int c = 0; c < 4; ++c)
#pragma unroll
                for (int r = 0; r < 4; ++r)
                    Pb[(size_t)(i * 64 + w * 16 + lg * 4 + r) * 70 + c * 16 + ln] =
                        bf16bits(S[i][c][r]);

        __builtin_amdgcn_s_setprio(1);
#pragma unroll
        for (int ks = 0; ks < 2; ++ks) {
            short8 pf0 = *(const short8*)&Pb[(size_t)(w * 16 + ln) * 70 + ks * 32 + lg * 8];
            short8 pf1 = *(const short8*)&Pb[(size_t)(64 + w * 16 + ln) * 70 + ks * 32 + lg * 8];
#pragma unroll
            for (int ct = 0; ct < 8; ++ct) {
                short8 vf = *(const short8*)&Vs[(size_t)(ct * 16 + ln) * 64 +
                                               (size_t)((ks * 4 + lg) ^ (ln & 7)) * 8];
                O[0][ct] = mfma16(pf0, vf, O[0][ct]);
                O[1][ct] = mfma16(pf1, vf, O[1][ct]);
            }
        }
        __builtin_amdgcn_s_setprio(0);
        __builtin_amdgcn_s_barrier();
    }

    if (nparts == 1) {
#pragma unroll
        for (int i = 0; i < 2; ++i)
#pragma unroll
            for (int r = 0; r < 4; ++r) {
                float inv = 1.f / l_[i][r];
                bf16* orow = attn + (size_t)(q0 + i * 64 + w * 16 + lg * 4 + r) * (NHEAD * DV) +
                             h * DV;
#pragma unroll
                for (int ct = 0; ct < 8; ++ct)
                    orow[ct * 16 + ln] = __float2bfloat16(O[i][ct][r] * inv);
            }
    } else {
        const int mlslot = h * 27 + (qt <= 10 ? (qt - 5) * 2 + part : 12 + (qt - 11) * 3 + part);
        float* mlp = ml + (size_t)mlslot * 128 * 2;
        if (part == 0) {
#pragma unroll
            for (int i = 0; i < 2; ++i)
#pragma unroll
                for (int r = 0; r < 4; ++r) {
                    const int rowb = i * 64 + w * 16 + lg * 4 + r;
                    bf16* orow = attn + (size_t)(q0 + rowb) * (NHEAD * DV) + h * DV;
#pragma unroll
                    for (int ct = 0; ct < 8; ++ct)
                        orow[ct * 16 + ln] = __float2bfloat16(O[i][ct][r]);
                    if (ln == 0) {
                        mlp[rowb * 2] = m_[i][r];
                        mlp[rowb * 2 + 1] = l_[i][r];
                    }
                }
        } else {
            const int oslot = h * 16 + (qt <= 10 ? (qt - 5) : 6 + (qt - 11) * 2 + (part - 1));
            bf16* op = Opart + (size_t)oslot * 128 * DV;
#pragma unroll
            for (int i = 0; i < 2; ++i)
#pragma unroll
                for (int r = 0; r < 4; ++r) {
                    const int rowb = i * 64 + w * 16 + lg * 4 + r;
#pragma unroll
                    for (int ct = 0; ct < 8; ++ct)
                        op[(size_t)rowb * DV + ct * 16 + ln] = __float2bfloat16(O[i][ct][r]);
                    if (ln == 0) {
                        mlp[rowb * 2] = m_[i][r];
                        mlp[rowb * 2 + 1] = l_[i][r];
                    }
                }
        }
    }
}

// Fused: blocks 0..175 merge split-K partials (qt=5..15, 2- or 3-way);
// blocks 176..1199 transpose w_o -> W4.
__global__ void finred_kernel(const bf16* __restrict__ Opart, const float* __restrict__ ml,
                              bf16* __restrict__ attn, const void* w_o, bf16* W4,
                              const int* flag) {
    const int bid = blockIdx.x;
    if (bid >= 176) {
        const int b = bid - 176;       // 0..1023
        const int n0 = (b & 31) * 64, k0 = (b >> 5) * 64;
        transpose_tile<HID_D>(w_o, W4, HID_D, n0, k0, 0, *flag);
        return;
    }
    const int qq = bid % 11;          // qt = 5+qq
    const int h = bid / 11;
    const int qt = 5 + qq;
    const int np = (qt <= 10) ? 2 : 3;
    const int q0 = qt * 128;
    const int tid = threadIdx.x;
    const int row = tid >> 1;         // 0..127
    const int dh = (tid & 1) * 64;
    float mp[3], lp[3], f[3];
    float mm = -1e30f;
    for (int p = 0; p < np; ++p) {
        const int msl = h * 27 + (qt <= 10 ? (qt - 5) * 2 + p : 12 + (qt - 11) * 3 + p);
        mp[p] = ml[((size_t)msl * 128 + row) * 2];
        lp[p] = ml[((size_t)msl * 128 + row) * 2 + 1];
        mm = fmaxf(mm, mp[p]);
    }
    float denom = 0.f;
    for (int p = 0; p < np; ++p) {
        f[p] = __expf(mp[p] - mm);
        denom += f[p] * lp[p];
    }
    const float inv = 1.f / denom;
    const int os1 = h * 16 + (qt <= 10 ? (qt - 5) : 6 + (qt - 11) * 2);
    bf16* arow = attn + (size_t)(q0 + row) * (NHEAD * DV) + h * DV + dh;
    const bf16* o1 = Opart + ((size_t)os1 * 128 + row) * DV + dh;
    const bf16* o2 = o1 + (size_t)128 * DV;
#pragma unroll
    for (int jc = 0; jc < 8; ++jc) {
        short8 a = *(const short8*)(arow + jc * 8);
        short8 b1 = *(const short8*)(o1 + jc * 8);
        short8 b2 = (np == 3) ? *(const short8*)(o2 + jc * 8) : b1;
        short8 o;
#pragma unroll
        for (int e = 0; e < 8; ++e) {
            float v = f[0] * b2f(a[e]) + f[1] * b2f(b1[e]);
            if (np == 3) v += f[2] * b2f(b2[e]);
            o[e] = bf16bits(v * inv);
        }
        *(short8*)(arow + jc * 8) = o;
    }
}

extern "C" void kernel_launch(void* const* d_in, const int* in_sizes, int n_in,
                              void* d_out, int out_size, void* d_ws, size_t ws_size,
                              hipStream_t stream) {
    const void* hidden = d_in[0];
    const void* cosb   = d_in[1];
    const void* sinb   = d_in[2];
    const void* w_qa   = d_in[3];
    const void* g_qa   = d_in[4];
    const void* w_qb   = d_in[5];
    const void* w_kva  = d_in[6];
    const void* g_kva  = d_in[7];
    const void* w_kvb  = d_in[8];
    const void* w_o    = d_in[9];

    // ws ~49.0 MB. Liveness-audited (same as rounds 7-9):
    //   qk_cat [2048][2176] (q_a cols 0..1535, ckv cols 1536..2175)
    //   BtCat / wqbT -> kn+vtb region (dead until G_kvb); wkvbT -> hbf
    //   attn -> ws start; ml -> ws+4.19M el; Opart -> hbf; W4 -> q region
    bf16* ws = (bf16*)d_ws;
    bf16* qk   = ws;                                         // 2048*2176
    bf16* ckvn = qk + (size_t)S_LEN * NCAT;                  // 2048*512
    bf16* q    = ckvn + (size_t)S_LEN * KVLORA;              // 2048*3072
    bf16* kn   = q + (size_t)S_LEN * NHEAD * DQK;            // 2048*2048
    bf16* vtb  = kn + (size_t)S_LEN * NHEAD * DNOPE;         // 2048*2048
    bf16* kpe  = vtb + (size_t)NHEAD * DV * S_LEN;           // 2048*64
    bf16* hbf  = kpe + (size_t)S_LEN * DROPE;                // 2048*2048
    int* flag  = (int*)(hbf + (size_t)S_LEN * HID_D);
    bf16* attn = ws;
    float* ml  = (float*)(ws + (size_t)S_LEN * HID_D);
    bf16* Opart = hbf;
    bf16* BtCat = kn;    // stage-1 transposed weights [2176][2048]
    bf16* wqbT  = kn;    // [3072][1536]
    bf16* wkvbT = hbf;   // [4096][512]
    bf16* W4    = q;     // [2048][2048]

    detect_kernel<<<1, 256, 0, stream>>>(hidden, flag);
    // convert + stage-1 weight transpose in one launch.
    prep1_kernel<<<dim3(3136), 256, 0, stream>>>(hidden, hbf, w_qa, w_kva, BtCat, flag);
    // Stage 1: fused GEMM N=2176 -> qk_cat.
    mgemm_kernel<0><<<dim3(NCAT / 128, S_LEN / 128), 256, 0, stream>>>(
        hbf, HID_D, BtCat, HID_D, qk, NCAT, HID_D, flag, nullptr, nullptr);
    // rmsnorm (q_a in place; ckv -> ckvn) + stage-2 weight transposes.
    prep2_kernel<<<dim3(5760), 256, 0, stream>>>(qk, g_qa, g_kva, ckvn,
                                                 w_qb, wqbT, w_kvb, wkvbT, flag);
    // q = q_a @ w_qb
    mgemm_kernel<0><<<dim3(NHEAD * DQK / 128, S_LEN / 128), 256, 0, stream>>>(
        qk, NCAT, wqbT, QLORA, q, NHEAD * DQK, QLORA, flag, nullptr, nullptr);
    // kn / vtb = ckvn @ w_kvb (split epilogue).
    mgemm_kernel<2><<<dim3(NHEAD * (DNOPE + DV) / 128, S_LEN / 128), 256, 0, stream>>>(
        ckvn, KVLORA, wkvbT, KVLORA, kn, NHEAD * (DNOPE + DV), KVLORA, flag, kn, vtb);
    // rope + attention
    rope_kernel<<<S_LEN, 576, 0, stream>>>(q, qk + QLORA, kpe, cosb, sinb, flag);
    fattn_kernel<<<dim3(512), 256, 0, stream>>>(q, kn, vtb, kpe, attn, Opart, ml);
    // merge partials + w_o transpose in one launch.
    finred_kernel<<<dim3(1200), 256, 0, stream>>>(Opart, ml, attn, w_o, W4, flag);
    // out = attn @ w_o
    mgemm_kernel<1><<<dim3(HID_D / 128, S_LEN / 128), 256, 0, stream>>>(
        attn, NHEAD * DV, W4, HID_D, d_out, HID_D, HID_D, flag, nullptr, nullptr);
}

// Round 12
// 327.716 us; speedup vs baseline: 1.0948x; 1.0948x over previous
//
#include <hip/hip_runtime.h>
#include <hip/hip_bf16.h>

#define S_LEN 2048
#define HID_D 2048
#define NHEAD 16
#define QLORA 1536
#define KVLORA 512
#define DNOPE 128
#define DROPE 64
#define DV 128
#define DQK 192
#define NCAT 2176           // QLORA + 640 (ckv padded): fused stage-1 N

#define KS_SH (64 * 192)    // 12288 shorts (24576 B) K buffer
#define VS_SH (128 * 64)    // 8192 shorts (16384 B) V buffer
#define BUF_SH (KS_SH + VS_SH)  // 40960 B per buffer; x2 = 81920 B -> 2 blocks/CU

typedef __hip_bfloat16 bf16;
typedef __attribute__((ext_vector_type(8))) short short8;
typedef __attribute__((ext_vector_type(4))) short s16x4;
typedef __attribute__((ext_vector_type(4))) float f32x4;

__device__ __forceinline__ float ldE(const float* p) { return *p; }
__device__ __forceinline__ float ldE(const bf16* p) { return __bfloat162float(*p); }
__device__ __forceinline__ void stE(float* p, float v) { *p = v; }
__device__ __forceinline__ void stE(bf16* p, float v) { *p = __float2bfloat16(v); }

__device__ __forceinline__ short bf16bits(float v) {
    __hip_bfloat16 h = __float2bfloat16(v);
    return *reinterpret_cast<short*>(&h);
}

// bf16 bit-pattern (as short, BY VALUE) -> float
__device__ __forceinline__ float b2f(short s) {
    union { short s; bf16 h; } u;
    u.s = s;
    return __bfloat162float(u.h);
}

__device__ __forceinline__ f32x4 mfma16(short8 a, short8 b, f32x4 c) {
    return __builtin_amdgcn_mfma_f32_16x16x32_bf16(a, b, c, 0, 0, 0);
}

// async global->LDS, 16B/lane. LDS dest = wave-uniform base + lane*16 (HW adds it).
__device__ __forceinline__ void gload16(const void* g, void* l) {
    __builtin_amdgcn_global_load_lds(
        (const __attribute__((address_space(1))) unsigned int*)g,
        (__attribute__((address_space(3))) unsigned int*)l, 16, 0, 0);
}

// Detect fp32 vs bf16 inputs by sniffing `hidden` as bf16 (parallel, 256 thr).
__global__ void detect_kernel(const void* hidden, int* flag) {
    __shared__ int red[256];
    const int tid = threadIdx.x;
    const bf16* hb = (const bf16*)hidden;
    float a = fabsf(__bfloat162float(hb[tid]));
    red[tid] = (!(a < 64.f) || (a != 0.f && a < 1e-30f)) ? 1 : 0;
    __syncthreads();
    for (int o = 128; o > 0; o >>= 1) {
        if (tid < o) red[tid] += red[tid + o];
        __syncthreads();
    }
    if (tid == 0) *flag = (red[0] > 16) ? 1 : 0;  // 1 => fp32
}

// Generic 64x64-tile transpose body: out[roff + n][KDIM] = in[k][n], zero n>=N.
template <int KDIM>
__device__ void transpose_tile(const void* in, bf16* out, int N, int n0, int k0,
                               int roff, int fp32) {
    __shared__ __align__(16) short Ts[64][80];
    const int tid = threadIdx.x;
    const bool inb = n0 < N;
    const int kl = tid >> 4;
    const int nl = (tid & 15) * 4;
#pragma unroll
    for (int p = 0; p < 4; ++p) {
        int k = kl + p * 16;
        float v[4] = {0.f, 0.f, 0.f, 0.f};
        if (inb) {
            if (fp32) {
                const float4 f = *(const float4*)((const float*)in + (size_t)(k0 + k) * N + n0 + nl);
                v[0] = f.x; v[1] = f.y; v[2] = f.z; v[3] = f.w;
            } else {
                const bf16* bp = (const bf16*)in + (size_t)(k0 + k) * N + n0 + nl;
#pragma unroll
                for (int i = 0; i < 4; ++i) v[i] = __bfloat162float(bp[i]);
            }
        }
#pragma unroll
        for (int i = 0; i < 4; ++i) Ts[nl + i][k] = bf16bits(v[i]);
    }
    __syncthreads();
    const int nr = tid >> 2;
    const int kq = (tid & 3) * 16;
    short* op = (short*)out + (size_t)(roff + n0 + nr) * KDIM + k0 + kq;
    *(short8*)op = *(short8*)&Ts[nr][kq];
    *(short8*)(op + 8) = *(short8*)&Ts[nr][kq + 8];
}

// Fused: blocks 0..2047 convert hidden -> hbf (bf16, 8 el/thread);
// blocks 2048..3135 transpose w_qa||w_kva -> BtCat (stage-1 weights).
__global__ void prep1_kernel(const void* hidden, bf16* hbf,
                             const void* w_qa, const void* w_kva, bf16* BtCat,
                             const int* flag) {
    const int bid = blockIdx.x;
    if (bid < 2048) {
        const int i = bid * 256 + threadIdx.x;  // < 524288 always
        size_t off = (size_t)i * 8;
        short8 o;
        if (*flag) {
            const float* f = (const float*)hidden + off;
#pragma unroll
            for (int j = 0; j < 8; ++j) o[j] = bf16bits(f[j]);
        } else {
            o = *(const short8*)((const short*)hidden + off);
        }
        *(short8*)((short*)hbf + off) = o;
    } else {
        const int b = bid - 2048;       // 0..1087
        const int bx = b % 34;
        const int k0 = (b / 34) * 64;
        const int fp32 = *flag;
        if (bx < 24) transpose_tile<HID_D>(w_qa, BtCat, QLORA, bx * 64, k0, 0, fp32);
        else transpose_tile<HID_D>(w_kva, BtCat, KVLORA + DROPE, (bx - 24) * 64, k0, QLORA, fp32);
    }
}

template <typename TG>
__device__ void rmsnorm_row(const bf16* __restrict__ xr, const TG* __restrict__ g,
                            bf16* __restrict__ yr, int len) {
    const int tid = threadIdx.x;
    float ss = 0.f;
    for (int i = tid; i < len; i += 256) {
        float v = __bfloat162float(xr[i]);
        ss += v * v;
    }
    __shared__ float red[256];
    red[tid] = ss;
    __syncthreads();
    for (int o = 128; o > 0; o >>= 1) {
        if (tid < o) red[tid] += red[tid + o];
        __syncthreads();
    }
    const float scale = rsqrtf(red[0] / (float)len + 1e-6f);
    for (int i = tid; i < len; i += 256)
        yr[i] = __float2bfloat16(__bfloat162float(xr[i]) * scale * ldE(&g[i]));
}

// Fused: blocks 0..4095 rmsnorm (q_a in place stride NCAT; ckv -> ckvn);
// blocks 4096..5759 transpose w_qb -> wqbT and w_kvb -> wkvbT.
__global__ void prep2_kernel(bf16* qk, const void* g_qa, const void* g_kva, bf16* ckvn,
                             const void* w_qb, bf16* wqbT,
                             const void* w_kvb, bf16* wkvbT, const int* flag) {
    const int bid = blockIdx.x;
    if (bid < 2 * S_LEN) {
        if (*flag) {
            if (bid < S_LEN)
                rmsnorm_row<float>(qk + (size_t)bid * NCAT, (const float*)g_qa,
                                   qk + (size_t)bid * NCAT, QLORA);
            else {
                const int s = bid - S_LEN;
                rmsnorm_row<float>(qk + (size_t)s * NCAT + QLORA, (const float*)g_kva,
                                   ckvn + (size_t)s * KVLORA, KVLORA);
            }
        } else {
            if (bid < S_LEN)
                rmsnorm_row<bf16>(qk + (size_t)bid * NCAT, (const bf16*)g_qa,
                                  qk + (size_t)bid * NCAT, QLORA);
            else {
                const int s = bid - S_LEN;
                rmsnorm_row<bf16>(qk + (size_t)s * NCAT + QLORA, (const bf16*)g_kva,
                                  ckvn + (size_t)s * KVLORA, KVLORA);
            }
        }
    } else {
        const int b = bid - 2 * S_LEN;   // 0..1663
        const int fp32 = *flag;
        if (b < 1152) {
            const int n0 = (b % 48) * 64, k0 = (b / 48) * 64;
            transpose_tile<QLORA>(w_qb, wqbT, NHEAD * DQK, n0, k0, 0, fp32);
        } else {
            const int bb = b - 1152;
            const int n0 = (bb % 64) * 64, k0 = (bb / 64) * 64;
            transpose_tile<KVLORA>(w_kvb, wkvbT, NHEAD * (DNOPE + DV), n0, k0, 0, fp32);
        }
    }
}

// C[M][N] = A[M][K] @ Bt[N][K]^T, bf16 in, fp32 acc. 128x128 tile, BK=64,
// 4 waves 2x2, each 64x64 = 4x4 mfma_16x16x32. DOUBLE-BUFFERED LDS (2x32KB,
// round-9 proven: 64KB keeps 2 blocks/CU residency — round 11's 3-buffer
// 96KB dropped to 1 block/CU and regressed 22us) with issue-ahead
// global_load_lds + counted s_waitcnt vmcnt(8). Shared array allocated ONCE
// in the wrapper (two inlined bodies would double-allocate).
// LDS [row][64], chunk c at pos c^(row&7): 0 conflicts. XCD-chunked swizzle.
// MODE 0: bf16 C. MODE 1: dtype by flag. MODE 2: KV split epilogue.
template <int MODE, typename TC>
__device__ void mgemm_body(short* __restrict__ AB,  // shared, 2*16384 shorts
                           const bf16* __restrict__ A, int lda,
                           const bf16* __restrict__ Bt, int ldb,
                           TC* __restrict__ C, int ldc, int K,
                           bf16* __restrict__ Kn, bf16* __restrict__ Vt) {
    const int tid = threadIdx.x;
    const int w = tid >> 6, lane = tid & 63;
    const int lg = lane >> 4, ln = lane & 15;
    const int wm = w >> 1, wn = w & 1;

    // XCD-chunked swizzle: blocks with flat%8==x run on XCD x (round-robin
    // dispatch) and receive the contiguous work chunk [x*cpx, (x+1)*cpx).
    const int nbx = gridDim.x;
    const int flat = blockIdx.y * nbx + blockIdx.x;
    const int cpx = (nbx * gridDim.y) >> 3;
    const int swz = (flat & 7) * cpx + (flat >> 3);
    const int m0 = (swz / nbx) * 128, n0 = (swz % nbx) * 128;

    int aO[4], bO[4];
#pragma unroll
    for (int p = 0; p < 4; ++p) {
        const int cid = tid + p * 256;
        const int row = cid >> 3, cpos = cid & 7;
        const int c = cpos ^ (row & 7);
        aO[p] = (m0 + row) * lda + c * 8;
        bO[p] = (n0 + row) * ldb + c * 8;
    }
    int aoff[2][4], boff[2][4];
#pragma unroll
    for (int hk = 0; hk < 2; ++hk)
#pragma unroll
        for (int i = 0; i < 4; ++i) {
            const int ra = wm * 64 + i * 16 + ln;
            const int rb = wn * 64 + i * 16 + ln;
            aoff[hk][i] = ra * 64 + ((hk * 4 + lg) ^ (ra & 7)) * 8;
            boff[hk][i] = rb * 64 + ((hk * 4 + lg) ^ (rb & 7)) * 8;
        }

    f32x4 acc[4][4];
#pragma unroll
    for (int i = 0; i < 4; ++i)
#pragma unroll
        for (int j = 0; j < 4; ++j) acc[i][j] = (f32x4){0.f, 0.f, 0.f, 0.f};

    const int nsteps = K >> 6;
    // Prologue: stage step 0 into buffer 0.
#pragma unroll
    for (int p = 0; p < 4; ++p) {
        gload16(A + (size_t)aO[p], AB + (w + 4 * p) * 512);
        gload16(Bt + (size_t)bO[p], AB + 8192 + (w + 4 * p) * 512);
    }

    for (int s = 0; s < nsteps; ++s) {
        const int cur = s & 1;
        const short* As = AB + cur * 16384;
        const short* Bs = As + 8192;
        // Issue next step's 8 loads into the other buffer (freed by the
        // previous iteration's end barrier), then counted-wait for THIS step's.
        if (s + 1 < nsteps) {
            const int k0n = (s + 1) * 64;
            short* AsN = AB + (cur ^ 1) * 16384;
            short* BsN = AsN + 8192;
#pragma unroll
            for (int p = 0; p < 4; ++p) {
                gload16(A + (size_t)aO[p] + k0n, AsN + (w + 4 * p) * 512);
                gload16(Bt + (size_t)bO[p] + k0n, BsN + (w + 4 * p) * 512);
            }
            asm volatile("s_waitcnt vmcnt(8)" ::: "memory");
        } else {
            asm volatile("s_waitcnt vmcnt(0)" ::: "memory");
        }
        __builtin_amdgcn_s_barrier();  // step s's A/B visible to all waves
        __builtin_amdgcn_s_setprio(1);
#pragma unroll
        for (int hk = 0; hk < 2; ++hk) {
            short8 af[4], bfr[4];
#pragma unroll
            for (int i = 0; i < 4; ++i) af[i] = *(const short8*)&As[aoff[hk][i]];
#pragma unroll
            for (int j = 0; j < 4; ++j) bfr[j] = *(const short8*)&Bs[boff[hk][j]];
#pragma unroll
            for (int i = 0; i < 4; ++i)
#pragma unroll
                for (int j = 0; j < 4; ++j) acc[i][j] = mfma16(af[i], bfr[j], acc[i][j]);
        }
        __builtin_amdgcn_s_setprio(0);
        __builtin_amdgcn_s_barrier();  // buf[cur] consumed -> may be restaged
    }
    if constexpr (MODE == 2) {
#pragma unroll
        for (int i = 0; i < 4; ++i)
#pragma unroll
            for (int j = 0; j < 4; ++j) {
                const int col = n0 + wn * 64 + j * 16 + ln;
                const int row = m0 + wm * 64 + i * 16 + lg * 4;  // %4 == 0
                const int h = col >> 8, d = col & 255;
                if (d < DNOPE) {
                    bf16* cp = Kn + (size_t)row * (NHEAD * DNOPE) + h * DNOPE + d;
#pragma unroll
                    for (int r = 0; r < 4; ++r)
                        cp[(size_t)r * (NHEAD * DNOPE)] = __float2bfloat16(acc[i][j][r]);
                } else {
                    s16x4 pk;
#pragma unroll
                    for (int r = 0; r < 4; ++r) pk[r] = bf16bits(acc[i][j][r]);
                    *(s16x4*)(Vt + (size_t)(h * DV + (d - DNOPE)) * S_LEN + row) = pk;
                }
            }
    } else {
#pragma unroll
        for (int i = 0; i < 4; ++i)
#pragma unroll
            for (int j = 0; j < 4; ++j) {
                TC* cp = C + (size_t)(m0 + wm * 64 + i * 16 + lg * 4) * ldc + n0 + wn * 64 +
                         j * 16 + ln;
#pragma unroll
                for (int r = 0; r < 4; ++r)
                    stE(cp + (size_t)r * ldc, acc[i][j][r]);
            }
    }
}

template <int MODE>
__global__ __launch_bounds__(256, 2)
void mgemm_kernel(const bf16* A, int lda, const bf16* Bt, int ldb, void* C, int ldc,
                  int K, const int* flag, bf16* Kn, bf16* Vt) {
    __shared__ __align__(16) short AB[2][16384];  // single 64KB allocation
    if (MODE == 1 && *flag)
        mgemm_body<1, float>(&AB[0][0], A, lda, Bt, ldb, (float*)C, ldc, K, nullptr, nullptr);
    else if (MODE == 2)
        mgemm_body<2, bf16>(&AB[0][0], A, lda, Bt, ldb, (bf16*)C, ldc, K, Kn, Vt);
    else
        mgemm_body<0, bf16>(&AB[0][0], A, lda, Bt, ldb, (bf16*)C, ldc, K, nullptr, nullptr);
}

// RoPE (deinterleave form): out[p] = x[2p]*c - x[2p+1]*s; out[p+32] = x[2p+1]*c + x[2p]*s.
// ckv = qk_cat + QLORA (row stride NCAT); k_pe raw at ckv[s][KVLORA..].
template <typename TG>
__device__ void rope_body(bf16* __restrict__ q, const bf16* __restrict__ ckv,
                          bf16* __restrict__ kpe, const TG* __restrict__ cosb,
                          const TG* __restrict__ sinb) {
    const int s = blockIdx.x;
    const int tid = threadIdx.x;  // blockDim = 576
    float x0 = 0.f, x1 = 0.f, c = 0.f, sn = 0.f;
    bf16* qbase = nullptr;
    int p = 0;
    const bool isq = tid < 512;
    const bool active = tid < 544;
    if (active) {
        if (isq) {
            const int h = tid >> 5;
            p = tid & 31;
            qbase = q + (size_t)s * (NHEAD * DQK) + h * DQK + DNOPE;
            x0 = __bfloat162float(qbase[2 * p]);
            x1 = __bfloat162float(qbase[2 * p + 1]);
        } else {
            p = tid - 512;
            const bf16* kb = ckv + (size_t)s * NCAT + KVLORA;
            x0 = __bfloat162float(kb[2 * p]);
            x1 = __bfloat162float(kb[2 * p + 1]);
        }
        c = ldE(&cosb[s * 64 + p]);
        sn = ldE(&sinb[s * 64 + p]);
    }
    __syncthreads();
    if (active) {
        if (isq) {
            qbase[p] = __float2bfloat16(x0 * c - x1 * sn);
            qbase[p + 32] = __float2bfloat16(x1 * c + x0 * sn);
        } else {
            kpe[s * 64 + p] = __float2bfloat16(x0 * c - x1 * sn);
            kpe[s * 64 + p + 32] = __float2bfloat16(x1 * c + x0 * sn);
        }
    }
}

__global__ void rope_kernel(bf16* q, const bf16* ckv, bf16* kpe,
                            const void* cosb, const void* sinb, const int* flag) {
    if (*flag) rope_body<float>(q, ckv, kpe, (const float*)cosb, (const float*)sinb);
    else       rope_body<bf16>(q, ckv, kpe, (const bf16*)cosb, (const bf16*)sinb);
}

// Flash-style MFMA attention (unchanged: 128-row q-tiles, split-K <=11,
// XCD-swizzled grid 512, double-buffered staging w/ counted vmcnt).
__global__ __launch_bounds__(256, 2)
void fattn_kernel(const bf16* __restrict__ q, const bf16* __restrict__ kn,
                  const bf16* __restrict__ vt, const bf16* __restrict__ kpe,
                  bf16* __restrict__ attn, bf16* __restrict__ Opart, float* __restrict__ ml) {
    const int nf = blockIdx.x;       // 0..511
    const int xcd = nf & 7;
    const int j = nf >> 3;           // 0..63
    const int bx = j & 31;
    const int h = (j >> 5) * 8 + xcd;
    int qt, part, nparts;
    if (bx < 15)      { qt = 15 - bx / 3;        part = bx % 3;        nparts = 3; }
    else if (bx < 27) { qt = 10 - (bx - 15) / 2; part = (bx - 15) & 1; nparts = 2; }
    else              { qt = 31 - bx;            part = 0;             nparts = 1; }
    const int nt = 2 * qt + 2;
    const int bsz = nt / nparts, rr = nt % nparts;
    const int t0 = part * bsz + (part < rr ? part : rr);
    const int t1 = t0 + bsz + (part < rr ? 1 : 0);
    const int q0 = qt * 128;

    const int tid = threadIdx.x;
    const int w = tid >> 6;
    const int l = tid & 63;
    const int lg = l >> 4;
    const int ln = l & 15;

    __shared__ __align__(16) short KV[2][BUF_SH];

    int offK[6], sK[6];
    bool isn[6];
#pragma unroll
    for (int p = 0; p < 6; ++p) {
        const int cid = tid + p * 256;
        const int row = cid / 24;
        const int cpos = cid % 24;
        const int c = (cpos & 24) | ((cpos & 7) ^ (row & 7));
        if (c < 16) {
            offK[p] = row * (NHEAD * DNOPE) + h * DNOPE + c * 8;
            sK[p] = NHEAD * DNOPE;
            isn[p] = true;
        } else {
            offK[p] = row * DROPE + (c - 16) * 8;
            sK[p] = DROPE;
            isn[p] = false;
        }
    }
    int offV[4];
#pragma unroll
    for (int p = 0; p < 4; ++p) {
        const int cid = tid + p * 256;
        const int row = cid >> 3;
        const int cc = (cid & 7) ^ (row & 7);
        offV[p] = (h * DV + row) * S_LEN + cc * 8;
    }

    short8 qf[2][6];
#pragma unroll
    for (int i = 0; i < 2; ++i) {
        const short* qrow =
            (const short*)(q + (size_t)(q0 + i * 64 + w * 16 + ln) * (NHEAD * DQK) + h * DQK);
#pragma unroll
        for (int ks = 0; ks < 6; ++ks)
            qf[i][ks] = *(const short8*)(qrow + ks * 32 + lg * 8);
    }

    f32x4 O[2][8];
#pragma unroll
    for (int i = 0; i < 2; ++i)
#pragma unroll
        for (int ct = 0; ct < 8; ++ct) O[i][ct] = (f32x4){0.f, 0.f, 0.f, 0.f};
    float m_[2][4], l_[2][4];
#pragma unroll
    for (int i = 0; i < 2; ++i)
#pragma unroll
        for (int r = 0; r < 4; ++r) { m_[i][r] = -1e30f; l_[i][r] = 0.f; }
    const float scale = 0.07216878364870322f;  // 192^-0.5

    {
        const int k0 = t0 * 64;
#pragma unroll
        for (int p = 0; p < 6; ++p) {
            const bf16* sp = (isn[p] ? kn : kpe) + (size_t)offK[p] + (size_t)k0 * sK[p];
            gload16(sp, &KV[0][0] + (w + 4 * p) * 512);
        }
#pragma unroll
        for (int p = 0; p < 4; ++p)
            gload16(vt + (size_t)offV[p] + k0, &KV[0][KS_SH] + (w + 4 * p) * 512);
    }

    for (int t = t0; t < t1; ++t) {
        const int cur = (t - t0) & 1;
        short* Ks = &KV[cur][0];
        short* Vs = &KV[cur][KS_SH];
        if (t + 1 < t1) {
            const int k0n = (t + 1) * 64;
            short* KsN = &KV[cur ^ 1][0];
            short* VsN = &KV[cur ^ 1][KS_SH];
#pragma unroll
            for (int p = 0; p < 6; ++p) {
                const bf16* sp = (isn[p] ? kn : kpe) + (size_t)offK[p] + (size_t)k0n * sK[p];
                gload16(sp, KsN + (w + 4 * p) * 512);
            }
#pragma unroll
            for (int p = 0; p < 4; ++p)
                gload16(vt + (size_t)offV[p] + k0n, VsN + (w + 4 * p) * 512);
            asm volatile("s_waitcnt vmcnt(10)" ::: "memory");
        } else {
            asm volatile("s_waitcnt vmcnt(0)" ::: "memory");
        }
        __builtin_amdgcn_s_barrier();

        const int k0 = t * 64;
        f32x4 S[2][4];
#pragma unroll
        for (int i = 0; i < 2; ++i)
#pragma unroll
            for (int c = 0; c < 4; ++c) S[i][c] = (f32x4){0.f, 0.f, 0.f, 0.f};
        __builtin_amdgcn_s_setprio(1);
#pragma unroll
        for (int ks = 0; ks < 6; ++ks) {
            const int kch = ks * 4 + lg;
#pragma unroll
            for (int c = 0; c < 4; ++c) {
                short8 kf = *(const short8*)&Ks[(size_t)(c * 16 + ln) * 192 +
                                               (size_t)(kch ^ (ln & 7)) * 8];
                S[0][c] = mfma16(qf[0][ks], kf, S[0][c]);
                S[1][c] = mfma16(qf[1][ks], kf, S[1][c]);
            }
        }
        __builtin_amdgcn_s_setprio(0);

        const int d0 = k0 - q0;
#pragma unroll
        for (int i = 0; i < 2; ++i)
#pragma unroll
            for (int c = 0; c < 4; ++c)
#pragma unroll
                for (int r = 0; r < 4; ++r) {
                    float v = S[i][c][r] * scale;
                    if (d0 > -64 &&
                        (d0 + c * 16 + ln) > (i * 64 + w * 16 + lg * 4 + r)) v = -1e30f;
                    S[i][c][r] = v;
                }

        float alpha[2][4];
#pragma unroll
        for (int i = 0; i < 2; ++i)
#pragma unroll
            for (int r = 0; r < 4; ++r) {
                float mx = fmaxf(fmaxf(S[i][0][r], S[i][1][r]), fmaxf(S[i][2][r], S[i][3][r]));
#pragma unroll
                for (int d = 1; d < 16; d <<= 1) mx = fmaxf(mx, __shfl_xor(mx, d));
                float mn = fmaxf(m_[i][r], mx);
                alpha[i][r] = __expf(m_[i][r] - mn);
                m_[i][r] = mn;
                float rs = 0.f;
#pragma unroll
                for (int c = 0; c < 4; ++c) {
                    float p = __expf(S[i][c][r] - mn);
                    S[i][c][r] = p;
                    rs += p;
                }
#pragma unroll
                for (int d = 1; d < 16; d <<= 1) rs += __shfl_xor(rs, d);
                l_[i][r] = l_[i][r] * alpha[i][r] + rs;
            }
#pragma unroll
        for (int i = 0; i < 2; ++i)
#pragma unroll
            for (int ct = 0; ct < 8; ++ct)
#pragma unroll
                for (int r = 0; r < 4; ++r) O[i][ct][r] *= alpha[i][r];

        __builtin_amdgcn_s_barrier();
        short* Pb = Ks;
#pragma unroll
        for (int i = 0; i < 2; ++i)
#pragma unroll
            for (int c = 0; c < 4; ++c)
#pragma unroll
                for (int r = 0; r < 4; ++r)
                    Pb[(size_t)(i * 64 + w * 16 + lg * 4 + r) * 70 + c * 16 + ln] =
                        bf16bits(S[i][c][r]);

        __builtin_amdgcn_s_setprio(1);
#pragma unroll
        for (int ks = 0; ks < 2; ++ks) {
            short8 pf0 = *(const short8*)&Pb[(size_t)(w * 16 + ln) * 70 + ks * 32 + lg * 8];
            short8 pf1 = *(const short8*)&Pb[(size_t)(64 + w * 16 + ln) * 70 + ks * 32 + lg * 8];
#pragma unroll
            for (int ct = 0; ct < 8; ++ct) {
                short8 vf = *(const short8*)&Vs[(size_t)(ct * 16 + ln) * 64 +
                                               (size_t)((ks * 4 + lg) ^ (ln & 7)) * 8];
                O[0][ct] = mfma16(pf0, vf, O[0][ct]);
                O[1][ct] = mfma16(pf1, vf, O[1][ct]);
            }
        }
        __builtin_amdgcn_s_setprio(0);
        __builtin_amdgcn_s_barrier();
    }

    if (nparts == 1) {
#pragma unroll
        for (int i = 0; i < 2; ++i)
#pragma unroll
            for (int r = 0; r < 4; ++r) {
                float inv = 1.f / l_[i][r];
                bf16* orow = attn + (size_t)(q0 + i * 64 + w * 16 + lg * 4 + r) * (NHEAD * DV) +
                             h * DV;
#pragma unroll
                for (int ct = 0; ct < 8; ++ct)
                    orow[ct * 16 + ln] = __float2bfloat16(O[i][ct][r] * inv);
            }
    } else {
        const int mlslot = h * 27 + (qt <= 10 ? (qt - 5) * 2 + part : 12 + (qt - 11) * 3 + part);
        float* mlp = ml + (size_t)mlslot * 128 * 2;
        if (part == 0) {
#pragma unroll
            for (int i = 0; i < 2; ++i)
#pragma unroll
                for (int r = 0; r < 4; ++r) {
                    const int rowb = i * 64 + w * 16 + lg * 4 + r;
                    bf16* orow = attn + (size_t)(q0 + rowb) * (NHEAD * DV) + h * DV;
#pragma unroll
                    for (int ct = 0; ct < 8; ++ct)
                        orow[ct * 16 + ln] = __float2bfloat16(O[i][ct][r]);
                    if (ln == 0) {
                        mlp[rowb * 2] = m_[i][r];
                        mlp[rowb * 2 + 1] = l_[i][r];
                    }
                }
        } else {
            const int oslot = h * 16 + (qt <= 10 ? (qt - 5) : 6 + (qt - 11) * 2 + (part - 1));
            bf16* op = Opart + (size_t)oslot * 128 * DV;
#pragma unroll
            for (int i = 0; i < 2; ++i)
#pragma unroll
                for (int r = 0; r < 4; ++r) {
                    const int rowb = i * 64 + w * 16 + lg * 4 + r;
#pragma unroll
                    for (int ct = 0; ct < 8; ++ct)
                        op[(size_t)rowb * DV + ct * 16 + ln] = __float2bfloat16(O[i][ct][r]);
                    if (ln == 0) {
                        mlp[rowb * 2] = m_[i][r];
                        mlp[rowb * 2 + 1] = l_[i][r];
                    }
                }
        }
    }
}

// Fused: blocks 0..175 merge split-K partials (qt=5..15, 2- or 3-way);
// blocks 176..1199 transpose w_o -> W4.
__global__ void finred_kernel(const bf16* __restrict__ Opart, const float* __restrict__ ml,
                              bf16* __restrict__ attn, const void* w_o, bf16* W4,
                              const int* flag) {
    const int bid = blockIdx.x;
    if (bid >= 176) {
        const int b = bid - 176;       // 0..1023
        const int n0 = (b & 31) * 64, k0 = (b >> 5) * 64;
        transpose_tile<HID_D>(w_o, W4, HID_D, n0, k0, 0, *flag);
        return;
    }
    const int qq = bid % 11;          // qt = 5+qq
    const int h = bid / 11;
    const int qt = 5 + qq;
    const int np = (qt <= 10) ? 2 : 3;
    const int q0 = qt * 128;
    const int tid = threadIdx.x;
    const int row = tid >> 1;         // 0..127
    const int dh = (tid & 1) * 64;
    float mp[3], lp[3], f[3];
    float mm = -1e30f;
    for (int p = 0; p < np; ++p) {
        const int msl = h * 27 + (qt <= 10 ? (qt - 5) * 2 + p : 12 + (qt - 11) * 3 + p);
        mp[p] = ml[((size_t)msl * 128 + row) * 2];
        lp[p] = ml[((size_t)msl * 128 + row) * 2 + 1];
        mm = fmaxf(mm, mp[p]);
    }
    float denom = 0.f;
    for (int p = 0; p < np; ++p) {
        f[p] = __expf(mp[p] - mm);
        denom += f[p] * lp[p];
    }
    const float inv = 1.f / denom;
    const int os1 = h * 16 + (qt <= 10 ? (qt - 5) : 6 + (qt - 11) * 2);
    bf16* arow = attn + (size_t)(q0 + row) * (NHEAD * DV) + h * DV + dh;
    const bf16* o1 = Opart + ((size_t)os1 * 128 + row) * DV + dh;
    const bf16* o2 = o1 + (size_t)128 * DV;
#pragma unroll
    for (int jc = 0; jc < 8; ++jc) {
        short8 a = *(const short8*)(arow + jc * 8);
        short8 b1 = *(const short8*)(o1 + jc * 8);
        short8 b2 = (np == 3) ? *(const short8*)(o2 + jc * 8) : b1;
        short8 o;
#pragma unroll
        for (int e = 0; e < 8; ++e) {
            float v = f[0] * b2f(a[e]) + f[1] * b2f(b1[e]);
            if (np == 3) v += f[2] * b2f(b2[e]);
            o[e] = bf16bits(v * inv);
        }
        *(short8*)(arow + jc * 8) = o;
    }
}

extern "C" void kernel_launch(void* const* d_in, const int* in_sizes, int n_in,
                              void* d_out, int out_size, void* d_ws, size_t ws_size,
                              hipStream_t stream) {
    const void* hidden = d_in[0];
    const void* cosb   = d_in[1];
    const void* sinb   = d_in[2];
    const void* w_qa   = d_in[3];
    const void* g_qa   = d_in[4];
    const void* w_qb   = d_in[5];
    const void* w_kva  = d_in[6];
    const void* g_kva  = d_in[7];
    const void* w_kvb  = d_in[8];
    const void* w_o    = d_in[9];

    // ws ~49.0 MB. Liveness-audited (same as rounds 7-11):
    //   qk_cat [2048][2176] (q_a cols 0..1535, ckv cols 1536..2175)
    //   BtCat / wqbT -> kn+vtb region (dead until G_kvb); wkvbT -> hbf
    //   attn -> ws start; ml -> ws+4.19M el; Opart -> hbf; W4 -> q region
    bf16* ws = (bf16*)d_ws;
    bf16* qk   = ws;                                         // 2048*2176
    bf16* ckvn = qk + (size_t)S_LEN * NCAT;                  // 2048*512
    bf16* q    = ckvn + (size_t)S_LEN * KVLORA;              // 2048*3072
    bf16* kn   = q + (size_t)S_LEN * NHEAD * DQK;            // 2048*2048
    bf16* vtb  = kn + (size_t)S_LEN * NHEAD * DNOPE;         // 2048*2048
    bf16* kpe  = vtb + (size_t)NHEAD * DV * S_LEN;           // 2048*64
    bf16* hbf  = kpe + (size_t)S_LEN * DROPE;                // 2048*2048
    int* flag  = (int*)(hbf + (size_t)S_LEN * HID_D);
    bf16* attn = ws;
    float* ml  = (float*)(ws + (size_t)S_LEN * HID_D);
    bf16* Opart = hbf;
    bf16* BtCat = kn;    // stage-1 transposed weights [2176][2048]
    bf16* wqbT  = kn;    // [3072][1536]
    bf16* wkvbT = hbf;   // [4096][512]
    bf16* W4    = q;     // [2048][2048]

    detect_kernel<<<1, 256, 0, stream>>>(hidden, flag);
    // convert + stage-1 weight transpose in one launch.
    prep1_kernel<<<dim3(3136), 256, 0, stream>>>(hidden, hbf, w_qa, w_kva, BtCat, flag);
    // Stage 1: fused GEMM N=2176 -> qk_cat.
    mgemm_kernel<0><<<dim3(NCAT / 128, S_LEN / 128), 256, 0, stream>>>(
        hbf, HID_D, BtCat, HID_D, qk, NCAT, HID_D, flag, nullptr, nullptr);
    // rmsnorm (q_a in place; ckv -> ckvn) + stage-2 weight transposes.
    prep2_kernel<<<dim3(5760), 256, 0, stream>>>(qk, g_qa, g_kva, ckvn,
                                                 w_qb, wqbT, w_kvb, wkvbT, flag);
    // q = q_a @ w_qb
    mgemm_kernel<0><<<dim3(NHEAD * DQK / 128, S_LEN / 128), 256, 0, stream>>>(
        qk, NCAT, wqbT, QLORA, q, NHEAD * DQK, QLORA, flag, nullptr, nullptr);
    // kn / vtb = ckvn @ w_kvb (split epilogue).
    mgemm_kernel<2><<<dim3(NHEAD * (DNOPE + DV) / 128, S_LEN / 128), 256, 0, stream>>>(
        ckvn, KVLORA, wkvbT, KVLORA, kn, NHEAD * (DNOPE + DV), KVLORA, flag, kn, vtb);
    // rope + attention
    rope_kernel<<<S_LEN, 576, 0, stream>>>(q, qk + QLORA, kpe, cosb, sinb, flag);
    fattn_kernel<<<dim3(512), 256, 0, stream>>>(q, kn, vtb, kpe, attn, Opart, ml);
    // merge partials + w_o transpose in one launch.
    finred_kernel<<<dim3(1200), 256, 0, stream>>>(Opart, ml, attn, w_o, W4, flag);
    // out = attn @ w_o
    mgemm_kernel<1><<<dim3(HID_D / 128, S_LEN / 128), 256, 0, stream>>>(
        attn, NHEAD * DV, W4, HID_D, d_out, HID_D, HID_D, flag, nullptr, nullptr);
}